// Round 1
// baseline (3393.165 us; speedup 1.0000x reference)
//
#include <hip/hip_runtime.h>
#include <stdint.h>

#define HIDDEN 4096
#define INTER  11008
#define NTOK   8192   // B*S = 4*2048

typedef __bf16 bf16;
typedef __bf16 bf16x8 __attribute__((ext_vector_type(8)));
typedef float  f32x4  __attribute__((ext_vector_type(4)));

__device__ __forceinline__ void gload16(const void* g, void* l) {
  __builtin_amdgcn_global_load_lds(
      (const __attribute__((address_space(1))) void*)g,
      (__attribute__((address_space(3))) void*)l, 16, 0, 0);
}

// ---------------- x: f32 -> bf16 ----------------
__global__ __launch_bounds__(256) void cvt_bf16_kernel(const float* __restrict__ x,
                                                       bf16* __restrict__ y) {
  const int i = (blockIdx.x * 256 + threadIdx.x) * 8;
  f32x4 a = *(const f32x4*)(x + i);
  f32x4 b = *(const f32x4*)(x + i + 4);
  bf16x8 v;
#pragma unroll
  for (int e = 0; e < 4; ++e) { v[e] = (bf16)a[e]; v[e + 4] = (bf16)b[e]; }
  *(bf16x8*)(y + i) = v;
}

// ---------------- GPTQ dequant -> W^T [J][Kout] bf16 ----------------
// qw: [Kout/8][J] u32 (rows packed, nibble e = row 8r+e)
// qz: [G][J/8]  u32 (cols packed, nibble j&7)
// sc: [G][J]    f32,  G = Kout/128, group g = k>>7 = r>>4
__global__ __launch_bounds__(256) void dequant_kernel(const uint32_t* __restrict__ qw,
                                                      const uint32_t* __restrict__ qz,
                                                      const float* __restrict__ sc,
                                                      bf16* __restrict__ out,
                                                      int J, int Kout) {
  __shared__ __align__(16) bf16 T[64 * 256];  // [64 j][256 k] 32KB, XOR-swizzled
  const int tid = threadIdx.x;
  const int tx = tid & 63, ty = tid >> 6;
  const int j0 = blockIdx.x * 64, r0 = blockIdx.y * 32;
  const int j = j0 + tx;
  const int J8 = J >> 3;
#pragma unroll
  for (int i = 0; i < 8; ++i) {
    const int r = r0 + ty * 8 + i;
    const int g = r >> 4;
    const uint32_t w = qw[(size_t)r * J + j];
    const float s = sc[(size_t)g * J + j];
    const uint32_t zb = (qz[(size_t)g * J8 + (j >> 3)] >> ((j & 7) * 4)) & 15u;
    const float zoff = (float)(zb + 1u);
    bf16x8 v;
#pragma unroll
    for (int e = 0; e < 8; ++e) {
      const float wv = (float)((w >> (e * 4)) & 15u);
      v[e] = (bf16)(s * (wv - zoff));
    }
    const int lb = (tx * 512 + (ty * 8 + i) * 16) ^ ((tx & 31) << 4);
    *(bf16x8*)((char*)T + lb) = v;
  }
  __syncthreads();
  // coalesced write-out: 2048 16B units, linear over [j][k]
#pragma unroll
  for (int u = 0; u < 8; ++u) {
    const int unit = u * 256 + tid;
    const int jj = unit >> 5;
    const int ob = (unit & 31) * 16;  // byte offset in row
    const int lb = (jj * 512 + ob) ^ ((jj & 31) << 4);
    bf16x8 v = *(const bf16x8*)((const char*)T + lb);
    *(bf16x8*)(out + (size_t)(j0 + jj) * Kout + r0 * 8 + (ob >> 1)) = v;
  }
}

// ---------------- GEMM1: h = silu(x@Wg) * (x@Wu), fused ----------------
// X: [M][4096] bf16, Wt: [22016][4096] bf16 (W^T; rows 0..INTER-1 = gate cols,
// INTER.. = up cols), H: [M][INTER] bf16. grid = (INTER/64, M/128).
__global__ __launch_bounds__(256) void gemm1_kernel(const bf16* __restrict__ X,
                                                    const bf16* __restrict__ Wt,
                                                    bf16* __restrict__ H) {
  __shared__ __align__(16) bf16 As[128 * 64];
  __shared__ __align__(16) bf16 Bgs[64 * 64];
  __shared__ __align__(16) bf16 Bus[64 * 64];
  const int tid = threadIdx.x;
  const int lane = tid & 63, w = tid >> 6;
  const int wr = w >> 1, wc = w & 1;
  const int fr = lane & 15, fg = lane >> 4;
  const int n0 = blockIdx.x * 64;
  const int m0 = blockIdx.y * 128;

  f32x4 ag[4][2], au[4][2];
#pragma unroll
  for (int mi = 0; mi < 4; ++mi)
#pragma unroll
    for (int nj = 0; nj < 2; ++nj) { ag[mi][nj] = (f32x4)0.0f; au[mi][nj] = (f32x4)0.0f; }

  for (int kt = 0; kt < HIDDEN / 64; ++kt) {
    const int k0 = kt * 64;
    // stage A tile [128][64]: 1024 16B chunks
#pragma unroll
    for (int i = 0; i < 4; ++i) {
      const int cb = w * 256 + i * 64;
      const int c = cb + lane;
      gload16(X + (size_t)(m0 + (c >> 3)) * HIDDEN + k0 + (c & 7) * 8, As + cb * 8);
    }
    // stage B gate/up tiles [64][64]: 512 chunks each
#pragma unroll
    for (int i = 0; i < 2; ++i) {
      const int cb = w * 128 + i * 64;
      const int c = cb + lane;
      gload16(Wt + (size_t)(n0 + (c >> 3)) * HIDDEN + k0 + (c & 7) * 8, Bgs + cb * 8);
      gload16(Wt + (size_t)(INTER + n0 + (c >> 3)) * HIDDEN + k0 + (c & 7) * 8, Bus + cb * 8);
    }
    __syncthreads();
#pragma unroll
    for (int kk = 0; kk < 2; ++kk) {
      bf16x8 a[4], bg[2], bu[2];
#pragma unroll
      for (int mi = 0; mi < 4; ++mi)
        a[mi] = *(const bf16x8*)(As + (wr * 64 + mi * 16 + fr) * 64 + kk * 32 + fg * 8);
#pragma unroll
      for (int nj = 0; nj < 2; ++nj) {
        bg[nj] = *(const bf16x8*)(Bgs + (wc * 32 + nj * 16 + fr) * 64 + kk * 32 + fg * 8);
        bu[nj] = *(const bf16x8*)(Bus + (wc * 32 + nj * 16 + fr) * 64 + kk * 32 + fg * 8);
      }
#pragma unroll
      for (int mi = 0; mi < 4; ++mi)
#pragma unroll
        for (int nj = 0; nj < 2; ++nj) {
          ag[mi][nj] = __builtin_amdgcn_mfma_f32_16x16x32_bf16(a[mi], bg[nj], ag[mi][nj], 0, 0, 0);
          au[mi][nj] = __builtin_amdgcn_mfma_f32_16x16x32_bf16(a[mi], bu[nj], au[mi][nj], 0, 0, 0);
        }
    }
    __syncthreads();
  }
  // epilogue: h = silu(g)*u, bf16
#pragma unroll
  for (int mi = 0; mi < 4; ++mi)
#pragma unroll
    for (int nj = 0; nj < 2; ++nj)
#pragma unroll
      for (int r = 0; r < 4; ++r) {
        const int row = m0 + wr * 64 + mi * 16 + fg * 4 + r;
        const int col = n0 + wc * 32 + nj * 16 + fr;
        const float gv = ag[mi][nj][r], uv = au[mi][nj][r];
        const float hv = gv / (1.0f + __expf(-gv)) * uv;
        H[(size_t)row * INTER + col] = (bf16)hv;
      }
}

// ---------------- GEMM2: out = h @ W_d (f32 out) ----------------
// Hm: [M][INTER] bf16, Wt: [4096][INTER] bf16 (W_d^T), Out: [M][4096] f32.
// grid = (HIDDEN/128, M/128)
__global__ __launch_bounds__(256) void gemm2_kernel(const bf16* __restrict__ Hm,
                                                    const bf16* __restrict__ Wt,
                                                    float* __restrict__ Out) {
  __shared__ __align__(16) bf16 As[128 * 64];
  __shared__ __align__(16) bf16 Bs[128 * 64];
  const int tid = threadIdx.x;
  const int lane = tid & 63, w = tid >> 6;
  const int wr = w >> 1, wc = w & 1;
  const int fr = lane & 15, fg = lane >> 4;
  const int n0 = blockIdx.x * 128;
  const int m0 = blockIdx.y * 128;

  f32x4 acc[4][4];
#pragma unroll
  for (int mi = 0; mi < 4; ++mi)
#pragma unroll
    for (int nj = 0; nj < 4; ++nj) acc[mi][nj] = (f32x4)0.0f;

  for (int kt = 0; kt < INTER / 64; ++kt) {
    const int k0 = kt * 64;
#pragma unroll
    for (int i = 0; i < 4; ++i) {
      const int cb = w * 256 + i * 64;
      const int c = cb + lane;
      gload16(Hm + (size_t)(m0 + (c >> 3)) * INTER + k0 + (c & 7) * 8, As + cb * 8);
    }
#pragma unroll
    for (int i = 0; i < 4; ++i) {
      const int cb = w * 256 + i * 64;
      const int c = cb + lane;
      gload16(Wt + (size_t)(n0 + (c >> 3)) * INTER + k0 + (c & 7) * 8, Bs + cb * 8);
    }
    __syncthreads();
#pragma unroll
    for (int kk = 0; kk < 2; ++kk) {
      bf16x8 a[4], b[4];
#pragma unroll
      for (int mi = 0; mi < 4; ++mi)
        a[mi] = *(const bf16x8*)(As + (wr * 64 + mi * 16 + fr) * 64 + kk * 32 + fg * 8);
#pragma unroll
      for (int nj = 0; nj < 4; ++nj)
        b[nj] = *(const bf16x8*)(Bs + (wc * 64 + nj * 16 + fr) * 64 + kk * 32 + fg * 8);
#pragma unroll
      for (int mi = 0; mi < 4; ++mi)
#pragma unroll
        for (int nj = 0; nj < 4; ++nj)
          acc[mi][nj] = __builtin_amdgcn_mfma_f32_16x16x32_bf16(a[mi], b[nj], acc[mi][nj], 0, 0, 0);
    }
    __syncthreads();
  }
#pragma unroll
  for (int mi = 0; mi < 4; ++mi)
#pragma unroll
    for (int nj = 0; nj < 4; ++nj)
#pragma unroll
      for (int r = 0; r < 4; ++r) {
        const int row = m0 + wr * 64 + mi * 16 + fg * 4 + r;
        const int col = n0 + wc * 64 + nj * 16 + fr;
        Out[(size_t)row * HIDDEN + col] = acc[mi][nj][r];
      }
}

extern "C" void kernel_launch(void* const* d_in, const int* in_sizes, int n_in,
                              void* d_out, int out_size, void* d_ws, size_t ws_size,
                              hipStream_t stream) {
  (void)in_sizes; (void)n_in; (void)out_size;
  const float*    x     = (const float*)d_in[0];
  const uint32_t* qw_gu = (const uint32_t*)d_in[1];
  const uint32_t* qz_gu = (const uint32_t*)d_in[2];
  const float*    sc_gu = (const float*)d_in[3];
  const uint32_t* qw_d  = (const uint32_t*)d_in[5];
  const uint32_t* qz_d  = (const uint32_t*)d_in[6];
  const float*    sc_d  = (const float*)d_in[7];
  float*          out   = (float*)d_out;

  char* ws = (char*)d_ws;
  const size_t XB = (size_t)NTOK * HIDDEN * 2;       // 67,108,864
  const size_t WT = (size_t)2 * INTER * HIDDEN * 2;  // 180,355,072 (holds W1t, later W2t)
  bf16* xb = (bf16*)ws;
  bf16* wt = (bf16*)(ws + XB);
  bf16* hb = (bf16*)(ws + XB + WT);
  const size_t avail_h = ws_size > (XB + WT) ? ws_size - (XB + WT) : 0;

  cvt_bf16_kernel<<<NTOK * HIDDEN / 2048, 256, 0, stream>>>(x, xb);

  if ((size_t)NTOK * INTER * 2 <= avail_h) {
    // full path
    dequant_kernel<<<dim3((2 * INTER) / 64, (HIDDEN / 8) / 32), 256, 0, stream>>>(
        qw_gu, qz_gu, sc_gu, wt, 2 * INTER, HIDDEN);
    gemm1_kernel<<<dim3(INTER / 64, NTOK / 128), 256, 0, stream>>>(xb, wt, hb);
    dequant_kernel<<<dim3(HIDDEN / 64, (INTER / 8) / 32), 256, 0, stream>>>(
        qw_d, qz_d, sc_d, wt, HIDDEN, INTER);
    gemm2_kernel<<<dim3(HIDDEN / 128, NTOK / 128), 256, 0, stream>>>(hb, wt, out);
  } else {
    // M-chunked fallback (smaller ws): re-dequant per chunk
    int chunk = NTOK;
    while ((size_t)chunk * INTER * 2 > avail_h && chunk > 128) chunk >>= 1;
    for (int mb = 0; mb < NTOK; mb += chunk) {
      dequant_kernel<<<dim3((2 * INTER) / 64, (HIDDEN / 8) / 32), 256, 0, stream>>>(
          qw_gu, qz_gu, sc_gu, wt, 2 * INTER, HIDDEN);
      gemm1_kernel<<<dim3(INTER / 64, chunk / 128), 256, 0, stream>>>(
          xb + (size_t)mb * HIDDEN, wt, hb);
      dequant_kernel<<<dim3(HIDDEN / 64, (INTER / 8) / 32), 256, 0, stream>>>(
          qw_d, qz_d, sc_d, wt, HIDDEN, INTER);
      gemm2_kernel<<<dim3(HIDDEN / 128, chunk / 128), 256, 0, stream>>>(
          hb, wt, out + (size_t)mb * HIDDEN);
    }
  }
}

// Round 2
// 2051.564 us; speedup vs baseline: 1.6539x; 1.6539x over previous
//
#include <hip/hip_runtime.h>
#include <stdint.h>

#define HIDDEN 4096
#define INTER  11008
#define NTOK   8192   // B*S = 4*2048

typedef __bf16 bf16;
typedef __bf16 bf16x8 __attribute__((ext_vector_type(8)));
typedef float  f32x4  __attribute__((ext_vector_type(4)));

__device__ __forceinline__ void gload16(const void* g, void* l) {
  __builtin_amdgcn_global_load_lds(
      (const __attribute__((address_space(1))) void*)g,
      (__attribute__((address_space(3))) void*)l, 16, 0, 0);
}

// ---------------- x: f32 -> bf16 ----------------
__global__ __launch_bounds__(256) void cvt_bf16_kernel(const float* __restrict__ x,
                                                       bf16* __restrict__ y) {
  const int i = (blockIdx.x * 256 + threadIdx.x) * 8;
  f32x4 a = *(const f32x4*)(x + i);
  f32x4 b = *(const f32x4*)(x + i + 4);
  bf16x8 v;
#pragma unroll
  for (int e = 0; e < 4; ++e) { v[e] = (bf16)a[e]; v[e + 4] = (bf16)b[e]; }
  *(bf16x8*)(y + i) = v;
}

// ---------------- GPTQ dequant -> W^T [rowmap(J)][Kout] bf16 ----------------
// ILV=true: gate col j -> row (j>>4)*32 + (j&15); up col j -> (j>>4)*32+16+(j&15)
template <bool ILV>
__global__ __launch_bounds__(256) void dequant_kernel(const uint32_t* __restrict__ qw,
                                                      const uint32_t* __restrict__ qz,
                                                      const float* __restrict__ sc,
                                                      bf16* __restrict__ out,
                                                      int J, int Kout) {
  __shared__ __align__(16) bf16 T[64 * 256];
  const int tid = threadIdx.x;
  const int tx = tid & 63, ty = tid >> 6;
  const int j0 = blockIdx.x * 64, r0 = blockIdx.y * 32;
  const int j = j0 + tx;
  const int J8 = J >> 3;
#pragma unroll
  for (int i = 0; i < 8; ++i) {
    const int r = r0 + ty * 8 + i;
    const int g = r >> 4;
    const uint32_t w = qw[(size_t)r * J + j];
    const float s = sc[(size_t)g * J + j];
    const uint32_t zb = (qz[(size_t)g * J8 + (j >> 3)] >> ((j & 7) * 4)) & 15u;
    const float zoff = (float)(zb + 1u);
    bf16x8 v;
#pragma unroll
    for (int e = 0; e < 8; ++e) {
      const float wv = (float)((w >> (e * 4)) & 15u);
      v[e] = (bf16)(s * (wv - zoff));
    }
    const int lb = (tx * 512 + (ty * 8 + i) * 16) ^ ((tx & 31) << 4);
    *(bf16x8*)((char*)T + lb) = v;
  }
  __syncthreads();
#pragma unroll
  for (int u = 0; u < 8; ++u) {
    const int unit = u * 256 + tid;
    const int jj = unit >> 5;
    const int ob = (unit & 31) * 16;
    const int lb = (jj * 512 + ob) ^ ((jj & 31) << 4);
    bf16x8 v = *(const bf16x8*)((const char*)T + lb);
    const int jg = j0 + jj;
    int rowm;
    if (ILV) {
      rowm = (jg < INTER) ? ((jg >> 4) * 32 + (jg & 15))
                          : (((jg - INTER) >> 4) * 32 + 16 + ((jg - INTER) & 15));
    } else {
      rowm = jg;
    }
    *(bf16x8*)(out + (size_t)rowm * Kout + r0 * 8 + (ob >> 1)) = v;
  }
}

// ---------------- 256x256 8-phase GEMM (m201-style template) ----------------
// A: [M][K] bf16 row-major. Bm: [Ntot][K] bf16 row-major (B^T).
// FUSED: Bm rows interleaved gate/up (32-row groups); writes H bf16 [M][INTER].
// else: writes f32 [M][HIDDEN]. grid = 32*(Ntot/256) flattened, 512 threads,
// 128 KiB dynamic LDS.
#define OFF_A 0
#define OFF_B 32768

#define STG(mat, buf, h, t)                                                    \
  do {                                                                         \
    gload16(s##mat[h][0] + (size_t)(t) * 128,                                  \
            lds + (buf) * 65536 + OFF_##mat + (h) * 16384 + w * 1024);         \
    gload16(s##mat[h][1] + (size_t)(t) * 128,                                  \
            lds + (buf) * 65536 + OFF_##mat + (h) * 16384 + 8192 + w * 1024);  \
  } while (0)

#define BAR __builtin_amdgcn_s_barrier()
#define LGKM0                                              \
  do {                                                     \
    asm volatile("s_waitcnt lgkmcnt(0)" ::: "memory");     \
    __builtin_amdgcn_sched_barrier(0);                     \
  } while (0)
#define VM6 asm volatile("s_waitcnt vmcnt(6)" ::: "memory")

#define MFMA_Q(MH, NH)                                                         \
  do {                                                                         \
    __builtin_amdgcn_s_setprio(1);                                             \
    _Pragma("unroll") for (int mi = 0; mi < 4; ++mi) {                         \
      _Pragma("unroll") for (int nj = 0; nj < 2; ++nj) {                       \
        acc[(MH)*4 + mi][(NH)*2 + nj] = __builtin_amdgcn_mfma_f32_16x16x32_bf16( \
            av[mi][0], bv[nj][0], acc[(MH)*4 + mi][(NH)*2 + nj], 0, 0, 0);     \
        acc[(MH)*4 + mi][(NH)*2 + nj] = __builtin_amdgcn_mfma_f32_16x16x32_bf16( \
            av[mi][1], bv[nj][1], acc[(MH)*4 + mi][(NH)*2 + nj], 0, 0, 0);     \
      }                                                                        \
    }                                                                          \
    __builtin_amdgcn_s_setprio(0);                                             \
    __builtin_amdgcn_sched_barrier(0);                                         \
  } while (0)

template <int K, int NT, bool FUSED>
__global__ __launch_bounds__(512, 2) void gemm8p(const bf16* __restrict__ A,
                                                 const bf16* __restrict__ Bm,
                                                 void* __restrict__ Cout) {
  extern __shared__ char lds[];
  const int tid = threadIdx.x;
  const int lane = tid & 63, w = tid >> 6;
  const int wr = w >> 2, wc = w & 3;
  const int fr = lane & 15, fg = lane >> 4;

  // bijective XCD swizzle (nwg % 8 == 0), m fastest within an XCD chunk
  const int nwg = gridDim.x;
  const int orig = blockIdx.x;
  const int wg = (orig & 7) * (nwg >> 3) + (orig >> 3);
  const int mb = wg & 31, nb = wg >> 5;
  const int m0 = mb << 8, n0 = nb << 8;

  // stage source pointers: linear LDS dest d -> (row r, swizzled col cL)
  const char* sA[2][2];
  const char* sB[2][2];
#pragma unroll
  for (int h = 0; h < 2; ++h)
#pragma unroll
    for (int l = 0; l < 2; ++l) {
      const int d = h * 16384 + (l * 512 + tid) * 16;
      const int r = d >> 7;
      const int c2 = d & 127;
      const int cL = c2 ^ ((r & 7) << 4);
      sA[h][l] = (const char*)A + (size_t)(m0 + r) * (size_t)(K * 2) + cL;
      sB[h][l] = (const char*)Bm + (size_t)(n0 + r) * (size_t)(K * 2) + cL;
    }

  const int swz = (fr & 7) << 4;
  const int ck[2] = {(fg * 16) ^ swz, (64 + fg * 16) ^ swz};
  const int aro = (wr * 64 + fr) * 128;            // + mh*16384 + mi*2048 + ck
  const int bro = OFF_B + (wc * 32 + fr) * 128;    // + nh*16384 + nj*2048 + ck

  auto lda = [&](int buf, int mh, int mi, int kk) -> bf16x8 {
    return *(const bf16x8*)(lds + buf * 65536 + mh * 16384 + aro + mi * 2048 + ck[kk]);
  };
  auto ldb = [&](int buf, int nh, int nj, int kk) -> bf16x8 {
    return *(const bf16x8*)(lds + buf * 65536 + bro + nh * 16384 + nj * 2048 + ck[kk]);
  };

  f32x4 acc[8][4];
#pragma unroll
  for (int i = 0; i < 8; ++i)
#pragma unroll
    for (int j = 0; j < 4; ++j) acc[i][j] = (f32x4)0.0f;
  bf16x8 av[4][2], bv[2][2];

  // prologue: tile0 fully (B0,A0,B1,A1) + tile1 {A0,B1,A1}; queue order matters
  STG(B, 0, 0, 0);
  STG(A, 0, 0, 0);
  STG(B, 0, 1, 0);
  STG(A, 0, 1, 0);
  STG(A, 1, 0, 1);
  STG(B, 1, 1, 1);
  STG(A, 1, 1, 1);
  VM6;  // tile0 landed; 3 half-tiles of tile1 in flight
  BAR;

  for (int t = 0; t < NT; ++t) {
    const int cb = t & 1, nx = cb ^ 1;
    const int t1 = (t + 1 < NT) ? t + 1 : 0;  // dummy stages keep vmcnt exact
    const int t2 = (t + 2 < NT) ? t + 2 : 0;

    // ---- ph1: read A-half0 + B-half0, stage (t+1).B0 -> nxt, MFMA Q(0,0)
#pragma unroll
    for (int mi = 0; mi < 4; ++mi) { av[mi][0] = lda(cb, 0, mi, 0); av[mi][1] = lda(cb, 0, mi, 1); }
#pragma unroll
    for (int nj = 0; nj < 2; ++nj) { bv[nj][0] = ldb(cb, 0, nj, 0); bv[nj][1] = ldb(cb, 0, nj, 1); }
    STG(B, nx, 0, t1);
    BAR; LGKM0;
    MFMA_Q(0, 0);
    BAR;

    // ---- ph2: read B-half1, stage (t+2).A0 -> cur (A0 dead), MFMA Q(0,1)
#pragma unroll
    for (int nj = 0; nj < 2; ++nj) { bv[nj][0] = ldb(cb, 1, nj, 0); bv[nj][1] = ldb(cb, 1, nj, 1); }
    STG(A, cb, 0, t2);
    BAR; LGKM0;
    MFMA_Q(0, 1);
    BAR;

    // ---- ph3: read A-half1, stage (t+2).B1 -> cur (B1 dead), MFMA Q(1,1)
#pragma unroll
    for (int mi = 0; mi < 4; ++mi) { av[mi][0] = lda(cb, 1, mi, 0); av[mi][1] = lda(cb, 1, mi, 1); }
    STG(B, cb, 1, t2);
    BAR; LGKM0;
    MFMA_Q(1, 1);
    BAR;

    // ---- ph4: re-read B-half0, stage (t+2).A1 -> cur (A1 dead), vmcnt(6), MFMA Q(1,0)
#pragma unroll
    for (int nj = 0; nj < 2; ++nj) { bv[nj][0] = ldb(cb, 0, nj, 0); bv[nj][1] = ldb(cb, 0, nj, 1); }
    STG(A, cb, 1, t2);
    VM6;
    BAR; LGKM0;
    MFMA_Q(1, 0);
    BAR;
  }

  // ---- epilogue
  if constexpr (FUSED) {
    bf16* H = (bf16*)Cout;
#pragma unroll
    for (int mh = 0; mh < 2; ++mh)
#pragma unroll
      for (int mi = 0; mi < 4; ++mi)
#pragma unroll
        for (int nh = 0; nh < 2; ++nh) {
          const f32x4 g = acc[mh * 4 + mi][nh * 2];
          const f32x4 u = acc[mh * 4 + mi][nh * 2 + 1];
          const int col = (n0 >> 1) + wc * 16 + nh * 64 + fr;
#pragma unroll
          for (int rr = 0; rr < 4; ++rr) {
            const int row = m0 + wr * 64 + mh * 128 + mi * 16 + fg * 4 + rr;
            const float gv = g[rr], uv = u[rr];
            H[(size_t)row * INTER + col] = (bf16)(gv / (1.0f + __expf(-gv)) * uv);
          }
        }
  } else {
    float* O = (float*)Cout;
#pragma unroll
    for (int mh = 0; mh < 2; ++mh)
#pragma unroll
      for (int mi = 0; mi < 4; ++mi)
#pragma unroll
        for (int nh = 0; nh < 2; ++nh)
#pragma unroll
          for (int nj = 0; nj < 2; ++nj) {
            const f32x4 a = acc[mh * 4 + mi][nh * 2 + nj];
            const int col = n0 + wc * 32 + nh * 128 + nj * 16 + fr;
#pragma unroll
            for (int rr = 0; rr < 4; ++rr) {
              const int row = m0 + wr * 64 + mh * 128 + mi * 16 + fg * 4 + rr;
              O[(size_t)row * HIDDEN + col] = a[rr];
            }
          }
  }
}

extern "C" void kernel_launch(void* const* d_in, const int* in_sizes, int n_in,
                              void* d_out, int out_size, void* d_ws, size_t ws_size,
                              hipStream_t stream) {
  (void)in_sizes; (void)n_in; (void)out_size; (void)ws_size;
  const float*    x     = (const float*)d_in[0];
  const uint32_t* qw_gu = (const uint32_t*)d_in[1];
  const uint32_t* qz_gu = (const uint32_t*)d_in[2];
  const float*    sc_gu = (const float*)d_in[3];
  const uint32_t* qw_d  = (const uint32_t*)d_in[5];
  const uint32_t* qz_d  = (const uint32_t*)d_in[6];
  const float*    sc_d  = (const float*)d_in[7];
  float*          out   = (float*)d_out;

  char* ws = (char*)d_ws;
  const size_t XB = (size_t)NTOK * HIDDEN * 2;       // 64 MiB
  const size_t WT = (size_t)2 * INTER * HIDDEN * 2;  // 172 MiB
  bf16* xb = (bf16*)ws;
  bf16* wt = (bf16*)(ws + XB);
  bf16* hb = (bf16*)(ws + XB + WT);

  // allow 128 KiB dynamic LDS (idempotent, host-side; safe under graph capture)
  hipFuncSetAttribute((const void*)&gemm8p<HIDDEN, HIDDEN / 64, true>,
                      hipFuncAttributeMaxDynamicSharedMemorySize, 131072);
  hipFuncSetAttribute((const void*)&gemm8p<INTER, INTER / 64, false>,
                      hipFuncAttributeMaxDynamicSharedMemorySize, 131072);

  cvt_bf16_kernel<<<NTOK * HIDDEN / 2048, 256, 0, stream>>>(x, xb);

  dequant_kernel<true><<<dim3((2 * INTER) / 64, (HIDDEN / 8) / 32), 256, 0, stream>>>(
      qw_gu, qz_gu, sc_gu, wt, 2 * INTER, HIDDEN);
  gemm8p<HIDDEN, HIDDEN / 64, true>
      <<<(2 * INTER / 256) * (NTOK / 256), 512, 131072, stream>>>(xb, wt, hb);

  dequant_kernel<false><<<dim3(HIDDEN / 64, (INTER / 8) / 32), 256, 0, stream>>>(
      qw_d, qz_d, sc_d, wt, HIDDEN, INTER);
  gemm8p<INTER, INTER / 64, false>
      <<<(HIDDEN / 256) * (NTOK / 256), 512, 131072, stream>>>(hb, wt, out);
}

// Round 3
// 2027.216 us; speedup vs baseline: 1.6738x; 1.0120x over previous
//
#include <hip/hip_runtime.h>
#include <stdint.h>

#define HIDDEN 4096
#define INTER  11008
#define NTOK   8192   // B*S = 4*2048

typedef __bf16 bf16;
typedef __bf16 bf16x8 __attribute__((ext_vector_type(8)));
typedef float  f32x4  __attribute__((ext_vector_type(4)));

__device__ __forceinline__ void gload16(const void* g, void* l) {
  __builtin_amdgcn_global_load_lds(
      (const __attribute__((address_space(1))) void*)g,
      (__attribute__((address_space(3))) void*)l, 16, 0, 0);
}

// ---------------- x: f32 -> bf16 ----------------
__global__ __launch_bounds__(256) void cvt_bf16_kernel(const float* __restrict__ x,
                                                       bf16* __restrict__ y) {
  const int i = (blockIdx.x * 256 + threadIdx.x) * 8;
  f32x4 a = *(const f32x4*)(x + i);
  f32x4 b = *(const f32x4*)(x + i + 4);
  bf16x8 v;
#pragma unroll
  for (int e = 0; e < 4; ++e) { v[e] = (bf16)a[e]; v[e + 4] = (bf16)b[e]; }
  *(bf16x8*)(y + i) = v;
}

// ---------------- GPTQ dequant -> W^T [rowmap(J)][Kout] bf16 ----------------
// ILV=true: gate col j -> row (j>>4)*32 + (j&15); up col j -> (j>>4)*32+16+(j&15)
template <bool ILV>
__global__ __launch_bounds__(256) void dequant_kernel(const uint32_t* __restrict__ qw,
                                                      const uint32_t* __restrict__ qz,
                                                      const float* __restrict__ sc,
                                                      bf16* __restrict__ out,
                                                      int J, int Kout) {
  __shared__ __align__(16) bf16 T[64 * 256];
  const int tid = threadIdx.x;
  const int tx = tid & 63, ty = tid >> 6;
  const int j0 = blockIdx.x * 64, r0 = blockIdx.y * 32;
  const int j = j0 + tx;
  const int J8 = J >> 3;
#pragma unroll
  for (int i = 0; i < 8; ++i) {
    const int r = r0 + ty * 8 + i;
    const int g = r >> 4;
    const uint32_t w = qw[(size_t)r * J + j];
    const float s = sc[(size_t)g * J + j];
    const uint32_t zb = (qz[(size_t)g * J8 + (j >> 3)] >> ((j & 7) * 4)) & 15u;
    const float zoff = (float)(zb + 1u);
    bf16x8 v;
#pragma unroll
    for (int e = 0; e < 8; ++e) {
      const float wv = (float)((w >> (e * 4)) & 15u);
      v[e] = (bf16)(s * (wv - zoff));
    }
    const int lb = (tx * 512 + (ty * 8 + i) * 16) ^ ((tx & 31) << 4);
    *(bf16x8*)((char*)T + lb) = v;
  }
  __syncthreads();
#pragma unroll
  for (int u = 0; u < 8; ++u) {
    const int unit = u * 256 + tid;
    const int jj = unit >> 5;
    const int ob = (unit & 31) * 16;
    const int lb = (jj * 512 + ob) ^ ((jj & 31) << 4);
    bf16x8 v = *(const bf16x8*)((const char*)T + lb);
    const int jg = j0 + jj;
    int rowm;
    if (ILV) {
      rowm = (jg < INTER) ? ((jg >> 4) * 32 + (jg & 15))
                          : (((jg - INTER) >> 4) * 32 + 16 + ((jg - INTER) & 15));
    } else {
      rowm = jg;
    }
    *(bf16x8*)(out + (size_t)rowm * Kout + r0 * 8 + (ob >> 1)) = v;
  }
}

// ---------------- 256x256 8-phase GEMM (m201-style template) ----------------
// A: [M][K] bf16 row-major. Bm: [Ntot][K] bf16 row-major (B^T).
// FUSED: Bm rows interleaved gate/up (32-row groups); writes H bf16 [M][INTER].
// else: writes f32 [M][HIDDEN]. grid = 32*NNB flattened, 512 threads,
// 128 KiB dynamic LDS. Within an XCD chunk, nb runs FASTEST so the X/A panel
// (2 MB) stays L2-resident and B is L3-shared across in-phase XCDs.
#define OFF_A 0
#define OFF_B 32768

#define STG(mat, buf, h, t)                                                    \
  do {                                                                         \
    gload16(s##mat[h][0] + (size_t)(t) * 128,                                  \
            lds + (buf) * 65536 + OFF_##mat + (h) * 16384 + w * 1024);         \
    gload16(s##mat[h][1] + (size_t)(t) * 128,                                  \
            lds + (buf) * 65536 + OFF_##mat + (h) * 16384 + 8192 + w * 1024);  \
  } while (0)

#define BAR __builtin_amdgcn_s_barrier()
#define LGKM0                                              \
  do {                                                     \
    asm volatile("s_waitcnt lgkmcnt(0)" ::: "memory");     \
    __builtin_amdgcn_sched_barrier(0);                     \
  } while (0)
#define VM6 asm volatile("s_waitcnt vmcnt(6)" ::: "memory")

#define MFMA_Q(MH, NH)                                                         \
  do {                                                                         \
    __builtin_amdgcn_s_setprio(1);                                             \
    _Pragma("unroll") for (int mi = 0; mi < 4; ++mi) {                         \
      _Pragma("unroll") for (int nj = 0; nj < 2; ++nj) {                       \
        acc[(MH)*4 + mi][(NH)*2 + nj] = __builtin_amdgcn_mfma_f32_16x16x32_bf16( \
            av[mi][0], bv[nj][0], acc[(MH)*4 + mi][(NH)*2 + nj], 0, 0, 0);     \
        acc[(MH)*4 + mi][(NH)*2 + nj] = __builtin_amdgcn_mfma_f32_16x16x32_bf16( \
            av[mi][1], bv[nj][1], acc[(MH)*4 + mi][(NH)*2 + nj], 0, 0, 0);     \
      }                                                                        \
    }                                                                          \
    __builtin_amdgcn_s_setprio(0);                                             \
    __builtin_amdgcn_sched_barrier(0);                                         \
  } while (0)

template <int K, int NT, int NNB, bool FUSED>
__global__ __launch_bounds__(512, 2) void gemm8p(const bf16* __restrict__ A,
                                                 const bf16* __restrict__ Bm,
                                                 void* __restrict__ Cout) {
  extern __shared__ char lds[];
  const int tid = threadIdx.x;
  const int lane = tid & 63, w = tid >> 6;
  const int wr = w >> 2, wc = w & 3;
  const int fr = lane & 15, fg = lane >> 4;

  // bijective XCD swizzle (nwg % 8 == 0); nb FASTEST within an XCD chunk
  const int nwg = gridDim.x;
  const int orig = blockIdx.x;
  const int wg = (orig & 7) * (nwg >> 3) + (orig >> 3);
  const int nb = wg % NNB, mb = wg / NNB;
  const int m0 = mb << 8, n0 = nb << 8;

  // stage source pointers: linear LDS dest d -> (row r, swizzled col cL)
  const char* sA[2][2];
  const char* sB[2][2];
#pragma unroll
  for (int h = 0; h < 2; ++h)
#pragma unroll
    for (int l = 0; l < 2; ++l) {
      const int d = h * 16384 + (l * 512 + tid) * 16;
      const int r = d >> 7;
      const int c2 = d & 127;
      const int cL = c2 ^ ((r & 7) << 4);
      sA[h][l] = (const char*)A + (size_t)(m0 + r) * (size_t)(K * 2) + cL;
      sB[h][l] = (const char*)Bm + (size_t)(n0 + r) * (size_t)(K * 2) + cL;
    }

  const int swz = (fr & 7) << 4;
  const int ck[2] = {(fg * 16) ^ swz, (64 + fg * 16) ^ swz};
  const int aro = (wr * 64 + fr) * 128;            // + mh*16384 + mi*2048 + ck
  const int bro = OFF_B + (wc * 32 + fr) * 128;    // + nh*16384 + nj*2048 + ck

  auto lda = [&](int buf, int mh, int mi, int kk) -> bf16x8 {
    return *(const bf16x8*)(lds + buf * 65536 + mh * 16384 + aro + mi * 2048 + ck[kk]);
  };
  auto ldb = [&](int buf, int nh, int nj, int kk) -> bf16x8 {
    return *(const bf16x8*)(lds + buf * 65536 + bro + nh * 16384 + nj * 2048 + ck[kk]);
  };

  f32x4 acc[8][4];
#pragma unroll
  for (int i = 0; i < 8; ++i)
#pragma unroll
    for (int j = 0; j < 4; ++j) acc[i][j] = (f32x4)0.0f;
  bf16x8 av[4][2], bv[2][2];

  // prologue: tile0 fully (B0,A0,B1,A1) + tile1 {A0,B1,A1}; queue order matters
  STG(B, 0, 0, 0);
  STG(A, 0, 0, 0);
  STG(B, 0, 1, 0);
  STG(A, 0, 1, 0);
  STG(A, 1, 0, 1);
  STG(B, 1, 1, 1);
  STG(A, 1, 1, 1);
  VM6;  // tile0 landed; 3 half-tiles of tile1 in flight
  BAR;

  for (int t = 0; t < NT; ++t) {
    const int cb = t & 1, nx = cb ^ 1;
    const int t1 = (t + 1 < NT) ? t + 1 : 0;  // dummy stages keep vmcnt exact
    const int t2 = (t + 2 < NT) ? t + 2 : 0;

    // ---- ph1: read A-half0 + B-half0, stage (t+1).B0 -> nxt, MFMA Q(0,0)
#pragma unroll
    for (int mi = 0; mi < 4; ++mi) { av[mi][0] = lda(cb, 0, mi, 0); av[mi][1] = lda(cb, 0, mi, 1); }
#pragma unroll
    for (int nj = 0; nj < 2; ++nj) { bv[nj][0] = ldb(cb, 0, nj, 0); bv[nj][1] = ldb(cb, 0, nj, 1); }
    STG(B, nx, 0, t1);
    BAR; LGKM0;
    MFMA_Q(0, 0);
    BAR;

    // ---- ph2: read B-half1, stage (t+2).A0 -> cur (A0 dead), MFMA Q(0,1)
#pragma unroll
    for (int nj = 0; nj < 2; ++nj) { bv[nj][0] = ldb(cb, 1, nj, 0); bv[nj][1] = ldb(cb, 1, nj, 1); }
    STG(A, cb, 0, t2);
    BAR; LGKM0;
    MFMA_Q(0, 1);
    BAR;

    // ---- ph3: read A-half1, stage (t+2).B1 -> cur (B1 dead), MFMA Q(1,1)
#pragma unroll
    for (int mi = 0; mi < 4; ++mi) { av[mi][0] = lda(cb, 1, mi, 0); av[mi][1] = lda(cb, 1, mi, 1); }
    STG(B, cb, 1, t2);
    BAR; LGKM0;
    MFMA_Q(1, 1);
    BAR;

    // ---- ph4: re-read B-half0, stage (t+2).A1 -> cur (A1 dead), vmcnt(6), MFMA Q(1,0)
#pragma unroll
    for (int nj = 0; nj < 2; ++nj) { bv[nj][0] = ldb(cb, 0, nj, 0); bv[nj][1] = ldb(cb, 0, nj, 1); }
    STG(A, cb, 1, t2);
    VM6;
    BAR; LGKM0;
    MFMA_Q(1, 0);
    BAR;
  }

  // ---- epilogue
  if constexpr (FUSED) {
    bf16* H = (bf16*)Cout;
#pragma unroll
    for (int mh = 0; mh < 2; ++mh)
#pragma unroll
      for (int mi = 0; mi < 4; ++mi)
#pragma unroll
        for (int nh = 0; nh < 2; ++nh) {
          const f32x4 g = acc[mh * 4 + mi][nh * 2];
          const f32x4 u = acc[mh * 4 + mi][nh * 2 + 1];
          const int col = (n0 >> 1) + wc * 16 + nh * 64 + fr;
#pragma unroll
          for (int rr = 0; rr < 4; ++rr) {
            const int row = m0 + wr * 64 + mh * 128 + mi * 16 + fg * 4 + rr;
            const float gv = g[rr], uv = u[rr];
            H[(size_t)row * INTER + col] = (bf16)(gv / (1.0f + __expf(-gv)) * uv);
          }
        }
  } else {
    float* O = (float*)Cout;
#pragma unroll
    for (int mh = 0; mh < 2; ++mh)
#pragma unroll
      for (int mi = 0; mi < 4; ++mi)
#pragma unroll
        for (int nh = 0; nh < 2; ++nh)
#pragma unroll
          for (int nj = 0; nj < 2; ++nj) {
            const f32x4 a = acc[mh * 4 + mi][nh * 2 + nj];
            const int col = n0 + wc * 32 + nh * 128 + nj * 16 + fr;
#pragma unroll
            for (int rr = 0; rr < 4; ++rr) {
              const int row = m0 + wr * 64 + mh * 128 + mi * 16 + fg * 4 + rr;
              O[(size_t)row * HIDDEN + col] = a[rr];
            }
          }
  }
}

extern "C" void kernel_launch(void* const* d_in, const int* in_sizes, int n_in,
                              void* d_out, int out_size, void* d_ws, size_t ws_size,
                              hipStream_t stream) {
  (void)in_sizes; (void)n_in; (void)out_size; (void)ws_size;
  const float*    x     = (const float*)d_in[0];
  const uint32_t* qw_gu = (const uint32_t*)d_in[1];
  const uint32_t* qz_gu = (const uint32_t*)d_in[2];
  const float*    sc_gu = (const float*)d_in[3];
  const uint32_t* qw_d  = (const uint32_t*)d_in[5];
  const uint32_t* qz_d  = (const uint32_t*)d_in[6];
  const float*    sc_d  = (const float*)d_in[7];
  float*          out   = (float*)d_out;

  char* ws = (char*)d_ws;
  const size_t XB = (size_t)NTOK * HIDDEN * 2;       // 64 MiB
  const size_t WT = (size_t)2 * INTER * HIDDEN * 2;  // 172 MiB
  bf16* xb = (bf16*)ws;
  bf16* wt = (bf16*)(ws + XB);
  bf16* hb = (bf16*)(ws + XB + WT);

  hipFuncSetAttribute((const void*)&gemm8p<HIDDEN, HIDDEN / 64, 2 * INTER / 256, true>,
                      hipFuncAttributeMaxDynamicSharedMemorySize, 131072);
  hipFuncSetAttribute((const void*)&gemm8p<INTER, INTER / 64, HIDDEN / 256, false>,
                      hipFuncAttributeMaxDynamicSharedMemorySize, 131072);

  cvt_bf16_kernel<<<NTOK * HIDDEN / 2048, 256, 0, stream>>>(x, xb);

  dequant_kernel<true><<<dim3((2 * INTER) / 64, (HIDDEN / 8) / 32), 256, 0, stream>>>(
      qw_gu, qz_gu, sc_gu, wt, 2 * INTER, HIDDEN);
  gemm8p<HIDDEN, HIDDEN / 64, 2 * INTER / 256, true>
      <<<(2 * INTER / 256) * (NTOK / 256), 512, 131072, stream>>>(xb, wt, hb);

  dequant_kernel<false><<<dim3(HIDDEN / 64, (INTER / 8) / 32), 256, 0, stream>>>(
      qw_d, qz_d, sc_d, wt, HIDDEN, INTER);
  gemm8p<INTER, INTER / 64, HIDDEN / 256, false>
      <<<(HIDDEN / 256) * (NTOK / 256), 512, 131072, stream>>>(hb, wt, out);
}

// Round 4
// 2015.020 us; speedup vs baseline: 1.6839x; 1.0061x over previous
//
#include <hip/hip_runtime.h>
#include <stdint.h>

#define HIDDEN 4096
#define INTER  11008
#define NTOK   8192   // B*S = 4*2048

typedef __bf16 bf16;
typedef __bf16 bf16x8 __attribute__((ext_vector_type(8)));
typedef float  f32x4  __attribute__((ext_vector_type(4)));

__device__ __forceinline__ void gload16(const void* g, void* l) {
  __builtin_amdgcn_global_load_lds(
      (const __attribute__((address_space(1))) void*)g,
      (__attribute__((address_space(3))) void*)l, 16, 0, 0);
}

// ---------------- x: f32 -> bf16 ----------------
__global__ __launch_bounds__(256) void cvt_bf16_kernel(const float* __restrict__ x,
                                                       bf16* __restrict__ y) {
  const int i = (blockIdx.x * 256 + threadIdx.x) * 8;
  f32x4 a = *(const f32x4*)(x + i);
  f32x4 b = *(const f32x4*)(x + i + 4);
  bf16x8 v;
#pragma unroll
  for (int e = 0; e < 4; ++e) { v[e] = (bf16)a[e]; v[e + 4] = (bf16)b[e]; }
  *(bf16x8*)(y + i) = v;
}

// ---------------- GPTQ dequant -> W^T [rowmap(J)][Kout] bf16 ----------------
// ILV=true: gate col j -> row (j>>4)*32 + (j&15); up col j -> (j>>4)*32+16+(j&15)
template <bool ILV>
__global__ __launch_bounds__(256) void dequant_kernel(const uint32_t* __restrict__ qw,
                                                      const uint32_t* __restrict__ qz,
                                                      const float* __restrict__ sc,
                                                      bf16* __restrict__ out,
                                                      int J, int Kout) {
  __shared__ __align__(16) bf16 T[64 * 256];
  const int tid = threadIdx.x;
  const int tx = tid & 63, ty = tid >> 6;
  const int j0 = blockIdx.x * 64, r0 = blockIdx.y * 32;
  const int j = j0 + tx;
  const int J8 = J >> 3;
#pragma unroll
  for (int i = 0; i < 8; ++i) {
    const int r = r0 + ty * 8 + i;
    const int g = r >> 4;
    const uint32_t w = qw[(size_t)r * J + j];
    const float s = sc[(size_t)g * J + j];
    const uint32_t zb = (qz[(size_t)g * J8 + (j >> 3)] >> ((j & 7) * 4)) & 15u;
    const float zoff = (float)(zb + 1u);
    bf16x8 v;
#pragma unroll
    for (int e = 0; e < 8; ++e) {
      const float wv = (float)((w >> (e * 4)) & 15u);
      v[e] = (bf16)(s * (wv - zoff));
    }
    const int lb = (tx * 512 + (ty * 8 + i) * 16) ^ ((tx & 31) << 4);
    *(bf16x8*)((char*)T + lb) = v;
  }
  __syncthreads();
#pragma unroll
  for (int u = 0; u < 8; ++u) {
    const int unit = u * 256 + tid;
    const int jj = unit >> 5;
    const int ob = (unit & 31) * 16;
    const int lb = (jj * 512 + ob) ^ ((jj & 31) << 4);
    bf16x8 v = *(const bf16x8*)((const char*)T + lb);
    const int jg = j0 + jj;
    int rowm;
    if (ILV) {
      rowm = (jg < INTER) ? ((jg >> 4) * 32 + (jg & 15))
                          : (((jg - INTER) >> 4) * 32 + 16 + ((jg - INTER) & 15));
    } else {
      rowm = jg;
    }
    *(bf16x8*)(out + (size_t)rowm * Kout + r0 * 8 + (ob >> 1)) = v;
  }
}

// ---------------- 256x256 8-phase GEMM (m201-style template) ----------------
// A: [M][K] bf16 row-major. Bm: [Ntot][K] bf16 row-major (B^T).
// FUSED: Bm rows interleaved gate/up (32-row groups); writes H bf16 [M][INTER].
// else: writes f32 [M][HIDDEN]. 512 threads, 128 KiB dynamic LDS.
// Block order: PLAIN launch order, mb-major / nb-fastest. The co-residency
// window (~256 blocks) then sweeps the grid globally: B stays L3-hot with tiny
// reuse distance (~3 A-panels of insertions between row sweeps), A read once.
// No XCD chunking — per-XCD sequential sweeps were shown (R2/R3) to blow the
// L3 reuse distance and fetch 3 GB instead of ~0.24 GB.
#define OFF_A 0
#define OFF_B 32768

#define STG(mat, buf, h, t)                                                    \
  do {                                                                         \
    gload16(s##mat[h][0] + (size_t)(t) * 128,                                  \
            lds + (buf) * 65536 + OFF_##mat + (h) * 16384 + w * 1024);         \
    gload16(s##mat[h][1] + (size_t)(t) * 128,                                  \
            lds + (buf) * 65536 + OFF_##mat + (h) * 16384 + 8192 + w * 1024);  \
  } while (0)

#define BAR __builtin_amdgcn_s_barrier()
#define LGKM0                                              \
  do {                                                     \
    asm volatile("s_waitcnt lgkmcnt(0)" ::: "memory");     \
    __builtin_amdgcn_sched_barrier(0);                     \
  } while (0)
#define VM6 asm volatile("s_waitcnt vmcnt(6)" ::: "memory")

#define MFMA_Q(MH, NH)                                                         \
  do {                                                                         \
    __builtin_amdgcn_s_setprio(1);                                             \
    _Pragma("unroll") for (int mi = 0; mi < 4; ++mi) {                         \
      _Pragma("unroll") for (int nj = 0; nj < 2; ++nj) {                       \
        acc[(MH)*4 + mi][(NH)*2 + nj] = __builtin_amdgcn_mfma_f32_16x16x32_bf16( \
            av[mi][0], bv[nj][0], acc[(MH)*4 + mi][(NH)*2 + nj], 0, 0, 0);     \
        acc[(MH)*4 + mi][(NH)*2 + nj] = __builtin_amdgcn_mfma_f32_16x16x32_bf16( \
            av[mi][1], bv[nj][1], acc[(MH)*4 + mi][(NH)*2 + nj], 0, 0, 0);     \
      }                                                                        \
    }                                                                          \
    __builtin_amdgcn_s_setprio(0);                                             \
    __builtin_amdgcn_sched_barrier(0);                                         \
  } while (0)

template <int K, int NT, int NNB, bool FUSED>
__global__ __launch_bounds__(512, 2) void gemm8p(const bf16* __restrict__ A,
                                                 const bf16* __restrict__ Bm,
                                                 void* __restrict__ Cout) {
  extern __shared__ char lds[];
  const int tid = threadIdx.x;
  const int lane = tid & 63, w = tid >> 6;
  const int wr = w >> 2, wc = w & 3;
  const int fr = lane & 15, fg = lane >> 4;

  // plain launch order: mb-major, nb-fastest (global rolling window)
  const int wg = blockIdx.x;
  const int nb = wg % NNB, mb = wg / NNB;
  const int m0 = mb << 8, n0 = nb << 8;

  // stage source pointers: linear LDS dest d -> (row r, swizzled col cL)
  const char* sA[2][2];
  const char* sB[2][2];
#pragma unroll
  for (int h = 0; h < 2; ++h)
#pragma unroll
    for (int l = 0; l < 2; ++l) {
      const int d = h * 16384 + (l * 512 + tid) * 16;
      const int r = d >> 7;
      const int c2 = d & 127;
      const int cL = c2 ^ ((r & 7) << 4);
      sA[h][l] = (const char*)A + (size_t)(m0 + r) * (size_t)(K * 2) + cL;
      sB[h][l] = (const char*)Bm + (size_t)(n0 + r) * (size_t)(K * 2) + cL;
    }

  const int swz = (fr & 7) << 4;
  const int ck[2] = {(fg * 16) ^ swz, (64 + fg * 16) ^ swz};
  const int aro = (wr * 64 + fr) * 128;            // + mh*16384 + mi*2048 + ck
  const int bro = OFF_B + (wc * 32 + fr) * 128;    // + nh*16384 + nj*2048 + ck

  auto lda = [&](int buf, int mh, int mi, int kk) -> bf16x8 {
    return *(const bf16x8*)(lds + buf * 65536 + mh * 16384 + aro + mi * 2048 + ck[kk]);
  };
  auto ldb = [&](int buf, int nh, int nj, int kk) -> bf16x8 {
    return *(const bf16x8*)(lds + buf * 65536 + bro + nh * 16384 + nj * 2048 + ck[kk]);
  };

  f32x4 acc[8][4];
#pragma unroll
  for (int i = 0; i < 8; ++i)
#pragma unroll
    for (int j = 0; j < 4; ++j) acc[i][j] = (f32x4)0.0f;
  bf16x8 av[4][2], bv[2][2];

  // prologue: tile0 fully (B0,A0,B1,A1) + tile1 {A0,B1,A1}; queue order matters
  STG(B, 0, 0, 0);
  STG(A, 0, 0, 0);
  STG(B, 0, 1, 0);
  STG(A, 0, 1, 0);
  STG(A, 1, 0, 1);
  STG(B, 1, 1, 1);
  STG(A, 1, 1, 1);
  VM6;  // tile0 landed; 3 half-tiles of tile1 in flight
  BAR;

  for (int t = 0; t < NT; ++t) {
    const int cb = t & 1, nx = cb ^ 1;
    const int t1 = (t + 1 < NT) ? t + 1 : 0;  // dummy stages keep vmcnt exact
    const int t2 = (t + 2 < NT) ? t + 2 : 0;

    // ---- ph1: read A-half0 + B-half0, stage (t+1).B0 -> nxt, MFMA Q(0,0)
#pragma unroll
    for (int mi = 0; mi < 4; ++mi) { av[mi][0] = lda(cb, 0, mi, 0); av[mi][1] = lda(cb, 0, mi, 1); }
#pragma unroll
    for (int nj = 0; nj < 2; ++nj) { bv[nj][0] = ldb(cb, 0, nj, 0); bv[nj][1] = ldb(cb, 0, nj, 1); }
    STG(B, nx, 0, t1);
    BAR; LGKM0;
    MFMA_Q(0, 0);
    BAR;

    // ---- ph2: read B-half1, stage (t+2).A0 -> cur (A0 dead), MFMA Q(0,1)
#pragma unroll
    for (int nj = 0; nj < 2; ++nj) { bv[nj][0] = ldb(cb, 1, nj, 0); bv[nj][1] = ldb(cb, 1, nj, 1); }
    STG(A, cb, 0, t2);
    BAR; LGKM0;
    MFMA_Q(0, 1);
    BAR;

    // ---- ph3: read A-half1, stage (t+2).B1 -> cur (B1 dead), MFMA Q(1,1)
#pragma unroll
    for (int mi = 0; mi < 4; ++mi) { av[mi][0] = lda(cb, 1, mi, 0); av[mi][1] = lda(cb, 1, mi, 1); }
    STG(B, cb, 1, t2);
    BAR; LGKM0;
    MFMA_Q(1, 1);
    BAR;

    // ---- ph4: re-read B-half0, stage (t+2).A1 -> cur (A1 dead), vmcnt(6), MFMA Q(1,0)
#pragma unroll
    for (int nj = 0; nj < 2; ++nj) { bv[nj][0] = ldb(cb, 0, nj, 0); bv[nj][1] = ldb(cb, 0, nj, 1); }
    STG(A, cb, 1, t2);
    VM6;
    BAR; LGKM0;
    MFMA_Q(1, 0);
    BAR;
  }

  // ---- epilogue
  if constexpr (FUSED) {
    bf16* H = (bf16*)Cout;
#pragma unroll
    for (int mh = 0; mh < 2; ++mh)
#pragma unroll
      for (int mi = 0; mi < 4; ++mi)
#pragma unroll
        for (int nh = 0; nh < 2; ++nh) {
          const f32x4 g = acc[mh * 4 + mi][nh * 2];
          const f32x4 u = acc[mh * 4 + mi][nh * 2 + 1];
          const int col = (n0 >> 1) + wc * 16 + nh * 64 + fr;
#pragma unroll
          for (int rr = 0; rr < 4; ++rr) {
            const int row = m0 + wr * 64 + mh * 128 + mi * 16 + fg * 4 + rr;
            const float gv = g[rr], uv = u[rr];
            H[(size_t)row * INTER + col] = (bf16)(gv / (1.0f + __expf(-gv)) * uv);
          }
        }
  } else {
    float* O = (float*)Cout;
#pragma unroll
    for (int mh = 0; mh < 2; ++mh)
#pragma unroll
      for (int mi = 0; mi < 4; ++mi)
#pragma unroll
        for (int nh = 0; nh < 2; ++nh)
#pragma unroll
          for (int nj = 0; nj < 2; ++nj) {
            const f32x4 a = acc[mh * 4 + mi][nh * 2 + nj];
            const int col = n0 + wc * 32 + nh * 128 + nj * 16 + fr;
#pragma unroll
            for (int rr = 0; rr < 4; ++rr) {
              const int row = m0 + wr * 64 + mh * 128 + mi * 16 + fg * 4 + rr;
              // out is never re-read: nontemporal keeps it from evicting hb/W2
              __builtin_nontemporal_store(a[rr], &O[(size_t)row * HIDDEN + col]);
            }
          }
  }
}

extern "C" void kernel_launch(void* const* d_in, const int* in_sizes, int n_in,
                              void* d_out, int out_size, void* d_ws, size_t ws_size,
                              hipStream_t stream) {
  (void)in_sizes; (void)n_in; (void)out_size; (void)ws_size;
  const float*    x     = (const float*)d_in[0];
  const uint32_t* qw_gu = (const uint32_t*)d_in[1];
  const uint32_t* qz_gu = (const uint32_t*)d_in[2];
  const float*    sc_gu = (const float*)d_in[3];
  const uint32_t* qw_d  = (const uint32_t*)d_in[5];
  const uint32_t* qz_d  = (const uint32_t*)d_in[6];
  const float*    sc_d  = (const float*)d_in[7];
  float*          out   = (float*)d_out;

  char* ws = (char*)d_ws;
  const size_t XB = (size_t)NTOK * HIDDEN * 2;       // 64 MiB
  const size_t WT = (size_t)2 * INTER * HIDDEN * 2;  // 172 MiB
  bf16* xb = (bf16*)ws;
  bf16* wt = (bf16*)(ws + XB);
  bf16* hb = (bf16*)(ws + XB + WT);

  hipFuncSetAttribute((const void*)&gemm8p<HIDDEN, HIDDEN / 64, 2 * INTER / 256, true>,
                      hipFuncAttributeMaxDynamicSharedMemorySize, 131072);
  hipFuncSetAttribute((const void*)&gemm8p<INTER, INTER / 64, HIDDEN / 256, false>,
                      hipFuncAttributeMaxDynamicSharedMemorySize, 131072);

  cvt_bf16_kernel<<<NTOK * HIDDEN / 2048, 256, 0, stream>>>(x, xb);

  dequant_kernel<true><<<dim3((2 * INTER) / 64, (HIDDEN / 8) / 32), 256, 0, stream>>>(
      qw_gu, qz_gu, sc_gu, wt, 2 * INTER, HIDDEN);
  gemm8p<HIDDEN, HIDDEN / 64, 2 * INTER / 256, true>
      <<<(2 * INTER / 256) * (NTOK / 256), 512, 131072, stream>>>(xb, wt, hb);

  dequant_kernel<false><<<dim3(HIDDEN / 64, (INTER / 8) / 32), 256, 0, stream>>>(
      qw_d, qz_d, sc_d, wt, HIDDEN, INTER);
  gemm8p<INTER, INTER / 64, HIDDEN / 256, false>
      <<<(HIDDEN / 256) * (NTOK / 256), 512, 131072, stream>>>(hb, wt, out);
}